// Round 2
// baseline (732.342 us; speedup 1.0000x reference)
//
#include <hip/hip_runtime.h>

#define H 64
#define G 64
#define OUT 2
#define SCAN_T 1024

// ---------------- zero int ----------------
__global__ void k_zero_int(int* p, int n) {
    int i = blockIdx.x * blockDim.x + threadIdx.x;
    if (i < n) p[i] = 0;
}

__global__ void k_zero(float* p, int n) {
    int i = blockIdx.x * blockDim.x + threadIdx.x;
    if (i < n) p[i] = 0.0f;
}

// ---------------- in-degree histogram ----------------
__global__ void k_hist(const int* __restrict__ dst, int* __restrict__ counts, int e) {
    int i = blockIdx.x * blockDim.x + threadIdx.x;
    if (i < e) atomicAdd(&counts[dst[i]], 1);
}

// ---------------- single-block exclusive scan + dinv ----------------
__global__ __launch_bounds__(SCAN_T) void k_scan(const int* __restrict__ counts,
                                                 int* __restrict__ rowptr,
                                                 int* __restrict__ cursor,
                                                 float* __restrict__ dinv,
                                                 int n, int e_total) {
    __shared__ int sums[SCAN_T];
    int t = threadIdx.x;
    int chunk = (n + SCAN_T - 1) / SCAN_T;
    int lo = t * chunk, hi = min(lo + chunk, n);
    int s = 0;
    for (int i = lo; i < hi; ++i) s += counts[i];
    sums[t] = s;
    __syncthreads();
    for (int off = 1; off < SCAN_T; off <<= 1) {
        int v = (t >= off) ? sums[t - off] : 0;
        __syncthreads();
        sums[t] += v;
        __syncthreads();
    }
    int base = (t == 0) ? 0 : sums[t - 1];
    for (int i = lo; i < hi; ++i) {
        rowptr[i] = base;
        cursor[i] = base;
        int c = counts[i];
        dinv[i] = rsqrtf((float)c + 1.0f);
        base += c;
    }
    if (t == SCAN_T - 1) rowptr[n] = e_total;
}

// ---------------- fill CSR: csr[pos] = {src, norm} ----------------
__global__ void k_fill(const int* __restrict__ src, const int* __restrict__ dst,
                       const float* __restrict__ dinv, int* __restrict__ cursor,
                       int2* __restrict__ csr, int e) {
    int i = blockIdx.x * blockDim.x + threadIdx.x;
    if (i < e) {
        int s = src[i], d = dst[i];
        int pos = atomicAdd(&cursor[d], 1);
        float nrm = dinv[s] * dinv[d];
        csr[pos] = make_int2(s, __float_as_int(nrm));
    }
}

// ---------------- 64x64 GEMM: Y[n,64] = X[n,64] @ W[64,64] ----------------
__global__ __launch_bounds__(256) void k_gemm64(const float* __restrict__ X,
                                                const float* __restrict__ W,
                                                float* __restrict__ Y, int n) {
    __shared__ float Ws[64][64];
    __shared__ float Xs[4][64];
    int tid = threadIdx.x;
    for (int i = tid; i < 64 * 64; i += 256) Ws[i >> 6][i & 63] = W[i];
    int r = tid >> 6;
    int c = tid & 63;
    int row = blockIdx.x * 4 + r;
    bool ok = (row < n);
    Xs[r][c] = ok ? X[(long long)row * 64 + c] : 0.0f;
    __syncthreads();
    float acc = 0.0f;
#pragma unroll
    for (int k = 0; k < 64; ++k) acc += Xs[r][k] * Ws[k][c];
    if (ok) Y[(long long)row * 64 + c] = acc;
}

// ---------------- fused aggregate: self-loop + gather-sum + bias + relu ----------------
// one wave per dst node, lane = channel
__global__ __launch_bounds__(256) void k_aggregate(const float* __restrict__ h,
                                                   const int2* __restrict__ csr,
                                                   const int* __restrict__ rowptr,
                                                   const float* __restrict__ dinv,
                                                   const float* __restrict__ b,
                                                   float* __restrict__ hout, int n) {
    int node = blockIdx.x * 4 + (threadIdx.x >> 6);
    int lane = threadIdx.x & 63;
    if (node >= n) return;
    float dd = dinv[node];
    float acc = h[(size_t)node * H + lane] * dd * dd;
    int r0 = rowptr[node], r1 = rowptr[node + 1];
    for (int e = r0; e < r1; ++e) {
        int2 p = csr[e];
        acc += h[(size_t)p.x * H + lane] * __int_as_float(p.y);
    }
    float v = acc + b[lane];
    hout[(size_t)node * H + lane] = v > 0.0f ? v : 0.0f;
}

// ---------------- graph boundaries (batch is sorted) ----------------
__global__ void k_bounds(const int* __restrict__ batch, int* __restrict__ starts, int n) {
    int t = blockIdx.x * blockDim.x + threadIdx.x;
    if (t > G) return;
    if (t == G) { starts[G] = n; return; }
    int lo = 0, hi = n;
    while (lo < hi) {
        int mid = (lo + hi) >> 1;
        if (batch[mid] < t) lo = mid + 1; else hi = mid;
    }
    starts[t] = lo;
}

// ---------------- pool: pooled[g] = sum h2 over graph rows ----------------
#define NSPLIT 16
__global__ __launch_bounds__(64) void k_pool(const float* __restrict__ h2,
                                             const int* __restrict__ starts,
                                             float* __restrict__ pooled) {
    int g = blockIdx.x / NSPLIT;
    int part = blockIdx.x % NSPLIT;
    int c = threadIdx.x;
    int s = starts[g], epos = starts[g + 1];
    int len = epos - s;
    if (len <= 0) return;
    int chunk = (len + NSPLIT - 1) / NSPLIT;
    int r0 = s + part * chunk;
    int r1 = min(r0 + chunk, epos);
    if (r0 >= r1) return;
    float acc = 0.0f;
    for (int r = r0; r < r1; ++r) acc += h2[(long long)r * H + c];
    atomicAdd(&pooled[g * H + c], acc);
}

// ---------------- final linear ----------------
__global__ void k_final(const float* __restrict__ pooled, const float* __restrict__ gf,
                        const float* __restrict__ Wlin, const float* __restrict__ blin,
                        float* __restrict__ out) {
    int t = threadIdx.x;
    if (t >= G * OUT) return;
    int g = t >> 1, o = t & 1;
    float acc = blin[o];
#pragma unroll
    for (int j = 0; j < 64; ++j) acc += pooled[g * H + j] * Wlin[j * OUT + o];
    acc += gf[g] * Wlin[64 * OUT + o];
    out[g * OUT + o] = acc;
}

extern "C" void kernel_launch(void* const* d_in, const int* in_sizes, int n_in,
                              void* d_out, int out_size, void* d_ws, size_t ws_size,
                              hipStream_t stream) {
    const float* x          = (const float*)d_in[0];
    const int*   edge_index = (const int*)d_in[1];
    const int*   batch      = (const int*)d_in[2];
    const float* gf         = (const float*)d_in[3];
    const float* W1         = (const float*)d_in[4];
    const float* b1         = (const float*)d_in[5];
    const float* W2         = (const float*)d_in[6];
    const float* b2         = (const float*)d_in[7];
    const float* Wlin       = (const float*)d_in[8];
    const float* blin       = (const float*)d_in[9];
    float* out = (float*)d_out;

    const int N = in_sizes[0] / H;
    const int E = in_sizes[1] / 2;
    const int* src = edge_index;
    const int* dst = edge_index + E;

    // workspace layout
    float* ws = (float*)d_ws;
    float* dinv   = ws;                        // N
    float* bufA   = dinv + N;                  // N*H
    float* bufB   = bufA + (size_t)N * H;      // N*H
    float* pooled = bufB + (size_t)N * H;      // G*H
    int*   starts = (int*)(pooled + G * H);    // G+1
    int*   counts = starts + (G + 1);          // N
    int*   rowptr = counts + N;                // N+1
    int*   cursor = rowptr + (N + 1);          // N
    // align csr to 8 bytes
    size_t off = (size_t)(cursor + N - (int*)d_ws);
    off = (off + 1) & ~(size_t)1;
    int2*  csr    = (int2*)((int*)d_ws + off); // E int2

    const int T = 256;

    // CSR build (also produces dinv from in-degree+1)
    k_zero_int<<<(N + T - 1) / T, T, 0, stream>>>(counts, N);
    k_hist<<<(E + T - 1) / T, T, 0, stream>>>(dst, counts, E);
    k_scan<<<1, SCAN_T, 0, stream>>>(counts, rowptr, cursor, dinv, N, E);
    k_fill<<<(E + T - 1) / T, T, 0, stream>>>(src, dst, dinv, cursor, csr, E);

    // layer 1
    k_gemm64<<<(N + 3) / 4, T, 0, stream>>>(x, W1, bufA, N);
    k_aggregate<<<(N + 3) / 4, T, 0, stream>>>(bufA, csr, rowptr, dinv, b1, bufB, N);

    // layer 2
    k_gemm64<<<(N + 3) / 4, T, 0, stream>>>(bufB, W2, bufA, N);
    k_aggregate<<<(N + 3) / 4, T, 0, stream>>>(bufA, csr, rowptr, dinv, b2, bufB, N);

    // pooling
    k_bounds<<<1, 128, 0, stream>>>(batch, starts, N);
    k_zero<<<(G * H + T - 1) / T, T, 0, stream>>>(pooled, G * H);
    k_pool<<<G * NSPLIT, 64, 0, stream>>>(bufB, starts, pooled);

    // head
    k_final<<<1, 128, 0, stream>>>(pooled, gf, Wlin, blin, out);
}

// Round 3
// 464.177 us; speedup vs baseline: 1.5777x; 1.5777x over previous
//
#include <hip/hip_runtime.h>

#define H 64
#define G 64
#define OUT 2
#define TILE 1024

// ---------------- zero ----------------
__global__ void k_zero_int(int* p, int n) {
    int i = blockIdx.x * blockDim.x + threadIdx.x;
    if (i < n) p[i] = 0;
}

__global__ void k_zero(float* p, int n) {
    int i = blockIdx.x * blockDim.x + threadIdx.x;
    if (i < n) p[i] = 0.0f;
}

// ---------------- in-degree histogram ----------------
__global__ void k_hist(const int* __restrict__ dst, int* __restrict__ counts, int e) {
    int i = blockIdx.x * blockDim.x + threadIdx.x;
    if (i < e) atomicAdd(&counts[dst[i]], 1);
}

// ---------------- 3-phase device-wide exclusive scan ----------------
// phase 1: per-block exclusive scan (block offset not applied) + block totals
__global__ __launch_bounds__(TILE) void k_scan1(const int* __restrict__ counts,
                                                int* __restrict__ rowptr,
                                                int* __restrict__ blocksums, int n) {
    __shared__ int sm[TILE];
    int t = threadIdx.x;
    int i = blockIdx.x * TILE + t;
    int v = (i < n) ? counts[i] : 0;
    sm[t] = v;
    __syncthreads();
    for (int off = 1; off < TILE; off <<= 1) {
        int u = (t >= off) ? sm[t - off] : 0;
        __syncthreads();
        sm[t] += u;
        __syncthreads();
    }
    if (i < n) rowptr[i] = sm[t] - v;  // exclusive
    if (t == TILE - 1) blocksums[blockIdx.x] = sm[t];
}

// phase 2: single small block scans block sums (exclusive, in place)
__global__ __launch_bounds__(256) void k_scan2(int* __restrict__ blocksums, int nb) {
    __shared__ int sm[256];
    int t = threadIdx.x;
    int v = (t < nb) ? blocksums[t] : 0;
    sm[t] = v;
    __syncthreads();
    for (int off = 1; off < 256; off <<= 1) {
        int u = (t >= off) ? sm[t - off] : 0;
        __syncthreads();
        sm[t] += u;
        __syncthreads();
    }
    if (t < nb) blocksums[t] = sm[t] - v;  // exclusive
}

// phase 3: add block offsets; produce cursor + dinv; cap rowptr
__global__ __launch_bounds__(TILE) void k_scan3(const int* __restrict__ counts,
                                                int* __restrict__ rowptr,
                                                int* __restrict__ cursor,
                                                float* __restrict__ dinv,
                                                const int* __restrict__ blocksums,
                                                int n, int e_total) {
    int i = blockIdx.x * TILE + threadIdx.x;
    if (i < n) {
        int r = rowptr[i] + blocksums[blockIdx.x];
        rowptr[i] = r;
        cursor[i] = r;
        dinv[i] = rsqrtf((float)counts[i] + 1.0f);
    }
    if (i == 0) rowptr[n] = e_total;
}

// ---------------- fill CSR: csr[pos] = {src, norm} ----------------
__global__ void k_fill(const int* __restrict__ src, const int* __restrict__ dst,
                       const float* __restrict__ dinv, int* __restrict__ cursor,
                       int2* __restrict__ csr, int e) {
    int i = blockIdx.x * blockDim.x + threadIdx.x;
    if (i < e) {
        int s = src[i], d = dst[i];
        int pos = atomicAdd(&cursor[d], 1);
        float nrm = dinv[s] * dinv[d];
        csr[pos] = make_int2(s, __float_as_int(nrm));
    }
}

// ---------------- 64x64 GEMM: Y[n,64] = X[n,64] @ W[64,64] ----------------
__global__ __launch_bounds__(256) void k_gemm64(const float* __restrict__ X,
                                                const float* __restrict__ W,
                                                float* __restrict__ Y, int n) {
    __shared__ float Ws[64][64];
    __shared__ float Xs[4][64];
    int tid = threadIdx.x;
    for (int i = tid; i < 64 * 64; i += 256) Ws[i >> 6][i & 63] = W[i];
    int r = tid >> 6;
    int c = tid & 63;
    int row = blockIdx.x * 4 + r;
    bool ok = (row < n);
    Xs[r][c] = ok ? X[(long long)row * 64 + c] : 0.0f;
    __syncthreads();
    float acc = 0.0f;
#pragma unroll
    for (int k = 0; k < 64; ++k) acc += Xs[r][k] * Ws[k][c];
    if (ok) Y[(long long)row * 64 + c] = acc;
}

// ---------------- fused aggregate: self-loop + gather-sum + bias + relu ----------------
// one wave per dst node, lane = channel
__global__ __launch_bounds__(256) void k_aggregate(const float* __restrict__ h,
                                                   const int2* __restrict__ csr,
                                                   const int* __restrict__ rowptr,
                                                   const float* __restrict__ dinv,
                                                   const float* __restrict__ b,
                                                   float* __restrict__ hout, int n) {
    int node = blockIdx.x * 4 + (threadIdx.x >> 6);
    int lane = threadIdx.x & 63;
    if (node >= n) return;
    float dd = dinv[node];
    float acc = h[(size_t)node * H + lane] * dd * dd;
    int r0 = rowptr[node], r1 = rowptr[node + 1];
    for (int e = r0; e < r1; ++e) {
        int2 p = csr[e];
        acc += h[(size_t)p.x * H + lane] * __int_as_float(p.y);
    }
    float v = acc + b[lane];
    hout[(size_t)node * H + lane] = v > 0.0f ? v : 0.0f;
}

// ---------------- graph boundaries (batch is sorted) ----------------
__global__ void k_bounds(const int* __restrict__ batch, int* __restrict__ starts, int n) {
    int t = blockIdx.x * blockDim.x + threadIdx.x;
    if (t > G) return;
    if (t == G) { starts[G] = n; return; }
    int lo = 0, hi = n;
    while (lo < hi) {
        int mid = (lo + hi) >> 1;
        if (batch[mid] < t) lo = mid + 1; else hi = mid;
    }
    starts[t] = lo;
}

// ---------------- pool ----------------
#define NSPLIT 16
__global__ __launch_bounds__(64) void k_pool(const float* __restrict__ h2,
                                             const int* __restrict__ starts,
                                             float* __restrict__ pooled) {
    int g = blockIdx.x / NSPLIT;
    int part = blockIdx.x % NSPLIT;
    int c = threadIdx.x;
    int s = starts[g], epos = starts[g + 1];
    int len = epos - s;
    if (len <= 0) return;
    int chunk = (len + NSPLIT - 1) / NSPLIT;
    int r0 = s + part * chunk;
    int r1 = min(r0 + chunk, epos);
    if (r0 >= r1) return;
    float acc = 0.0f;
    for (int r = r0; r < r1; ++r) acc += h2[(long long)r * H + c];
    atomicAdd(&pooled[g * H + c], acc);
}

// ---------------- final linear ----------------
__global__ void k_final(const float* __restrict__ pooled, const float* __restrict__ gf,
                        const float* __restrict__ Wlin, const float* __restrict__ blin,
                        float* __restrict__ out) {
    int t = threadIdx.x;
    if (t >= G * OUT) return;
    int g = t >> 1, o = t & 1;
    float acc = blin[o];
#pragma unroll
    for (int j = 0; j < 64; ++j) acc += pooled[g * H + j] * Wlin[j * OUT + o];
    acc += gf[g] * Wlin[64 * OUT + o];
    out[g * OUT + o] = acc;
}

extern "C" void kernel_launch(void* const* d_in, const int* in_sizes, int n_in,
                              void* d_out, int out_size, void* d_ws, size_t ws_size,
                              hipStream_t stream) {
    const float* x          = (const float*)d_in[0];
    const int*   edge_index = (const int*)d_in[1];
    const int*   batch      = (const int*)d_in[2];
    const float* gf         = (const float*)d_in[3];
    const float* W1         = (const float*)d_in[4];
    const float* b1         = (const float*)d_in[5];
    const float* W2         = (const float*)d_in[6];
    const float* b2         = (const float*)d_in[7];
    const float* Wlin       = (const float*)d_in[8];
    const float* blin       = (const float*)d_in[9];
    float* out = (float*)d_out;

    const int N = in_sizes[0] / H;
    const int E = in_sizes[1] / 2;
    const int* src = edge_index;
    const int* dst = edge_index + E;

    // workspace layout
    float* ws = (float*)d_ws;
    float* dinv   = ws;                        // N
    float* bufA   = dinv + N;                  // N*H
    float* bufB   = bufA + (size_t)N * H;      // N*H
    float* pooled = bufB + (size_t)N * H;      // G*H
    int*   starts = (int*)(pooled + G * H);    // G+1
    int*   counts = starts + (G + 1);          // N
    int*   rowptr = counts + N;                // N+1
    int*   cursor = rowptr + (N + 1);          // N
    int*   blocksums = cursor + N;             // up to 256
    // align csr to 8 bytes
    size_t off = (size_t)(blocksums + 256 - (int*)d_ws);
    off = (off + 1) & ~(size_t)1;
    int2*  csr    = (int2*)((int*)d_ws + off); // E int2

    const int T = 256;
    const int NB = (N + TILE - 1) / TILE;  // 98 for N=100k (<=256 required)

    // CSR build (also produces dinv from in-degree+1)
    k_zero_int<<<(N + T - 1) / T, T, 0, stream>>>(counts, N);
    k_hist<<<(E + T - 1) / T, T, 0, stream>>>(dst, counts, E);
    k_scan1<<<NB, TILE, 0, stream>>>(counts, rowptr, blocksums, N);
    k_scan2<<<1, 256, 0, stream>>>(blocksums, NB);
    k_scan3<<<NB, TILE, 0, stream>>>(counts, rowptr, cursor, dinv, blocksums, N, E);
    k_fill<<<(E + T - 1) / T, T, 0, stream>>>(src, dst, dinv, cursor, csr, E);

    // layer 1
    k_gemm64<<<(N + 3) / 4, T, 0, stream>>>(x, W1, bufA, N);
    k_aggregate<<<(N + 3) / 4, T, 0, stream>>>(bufA, csr, rowptr, dinv, b1, bufB, N);

    // layer 2
    k_gemm64<<<(N + 3) / 4, T, 0, stream>>>(bufB, W2, bufA, N);
    k_aggregate<<<(N + 3) / 4, T, 0, stream>>>(bufA, csr, rowptr, dinv, b2, bufB, N);

    // pooling
    k_bounds<<<1, 128, 0, stream>>>(batch, starts, N);
    k_zero<<<(G * H + T - 1) / T, T, 0, stream>>>(pooled, G * H);
    k_pool<<<G * NSPLIT, 64, 0, stream>>>(bufB, starts, pooled);

    // head
    k_final<<<1, 128, 0, stream>>>(pooled, gf, Wlin, blin, out);
}

// Round 4
// 270.665 us; speedup vs baseline: 2.7057x; 1.7149x over previous
//
#include <hip/hip_runtime.h>

#define H 64
#define G 64
#define OUT 2
#define TILE 1024

// ---------------- zero ----------------
__global__ void k_zero_int(int* p, int n) {
    int i = blockIdx.x * blockDim.x + threadIdx.x;
    if (i < n) p[i] = 0;
}

__global__ void k_zero(float* p, int n) {
    int i = blockIdx.x * blockDim.x + threadIdx.x;
    if (i < n) p[i] = 0.0f;
}

// ---------------- in-degree histogram ----------------
__global__ void k_hist(const int* __restrict__ dst, int* __restrict__ counts, int e) {
    int i = blockIdx.x * blockDim.x + threadIdx.x;
    if (i < e) atomicAdd(&counts[dst[i]], 1);
}

// ---------------- 3-phase device-wide exclusive scan ----------------
__global__ __launch_bounds__(TILE) void k_scan1(const int* __restrict__ counts,
                                                int* __restrict__ rowptr,
                                                int* __restrict__ blocksums, int n) {
    __shared__ int sm[TILE];
    int t = threadIdx.x;
    int i = blockIdx.x * TILE + t;
    int v = (i < n) ? counts[i] : 0;
    sm[t] = v;
    __syncthreads();
    for (int off = 1; off < TILE; off <<= 1) {
        int u = (t >= off) ? sm[t - off] : 0;
        __syncthreads();
        sm[t] += u;
        __syncthreads();
    }
    if (i < n) rowptr[i] = sm[t] - v;  // exclusive
    if (t == TILE - 1) blocksums[blockIdx.x] = sm[t];
}

__global__ __launch_bounds__(256) void k_scan2(int* __restrict__ blocksums, int nb) {
    __shared__ int sm[256];
    int t = threadIdx.x;
    int v = (t < nb) ? blocksums[t] : 0;
    sm[t] = v;
    __syncthreads();
    for (int off = 1; off < 256; off <<= 1) {
        int u = (t >= off) ? sm[t - off] : 0;
        __syncthreads();
        sm[t] += u;
        __syncthreads();
    }
    if (t < nb) blocksums[t] = sm[t] - v;
}

__global__ __launch_bounds__(TILE) void k_scan3(const int* __restrict__ counts,
                                                int* __restrict__ rowptr,
                                                int* __restrict__ cursor,
                                                float* __restrict__ dinv,
                                                const int* __restrict__ blocksums,
                                                int n, int e_total) {
    int i = blockIdx.x * TILE + threadIdx.x;
    if (i < n) {
        int r = rowptr[i] + blocksums[blockIdx.x];
        rowptr[i] = r;
        cursor[i] = r;
        dinv[i] = rsqrtf((float)counts[i] + 1.0f);
    }
    if (i == 0) rowptr[n] = e_total;
}

// ---------------- fill CSR: csr[pos] = {src, norm} ----------------
__global__ void k_fill(const int* __restrict__ src, const int* __restrict__ dst,
                       const float* __restrict__ dinv, int* __restrict__ cursor,
                       int2* __restrict__ csr, int e) {
    int i = blockIdx.x * blockDim.x + threadIdx.x;
    if (i < e) {
        int s = src[i], d = dst[i];
        int pos = atomicAdd(&cursor[d], 1);
        float nrm = dinv[s] * dinv[d];
        csr[pos] = make_int2(s, __float_as_int(nrm));
    }
}

// ---------------- GEMM: Y[n,64] = X[n,64] @ W[64,64], W in VGPRs, X via s_load ----------------
__global__ __launch_bounds__(256) void k_gemm64(const float* __restrict__ X,
                                                const float* __restrict__ W,
                                                float* __restrict__ Y, int n) {
    int lane = threadIdx.x & 63;
    int wave = __builtin_amdgcn_readfirstlane(threadIdx.x >> 6);
    // wreg[k] = W[k][lane]
    float wreg[64];
#pragma unroll
    for (int k = 0; k < 64; ++k) wreg[k] = W[k * 64 + lane];
    int base = blockIdx.x * 16 + wave * 4;  // 4 rows per wave
    int r0 = min(base + 0, n - 1);
    int r1 = min(base + 1, n - 1);
    int r2 = min(base + 2, n - 1);
    int r3 = min(base + 3, n - 1);
    const float* x0 = X + (size_t)r0 * 64;
    const float* x1 = X + (size_t)r1 * 64;
    const float* x2 = X + (size_t)r2 * 64;
    const float* x3 = X + (size_t)r3 * 64;
    float a0 = 0.f, a1 = 0.f, a2 = 0.f, a3 = 0.f;
#pragma unroll
    for (int k = 0; k < 64; ++k) {
        float w = wreg[k];
        a0 += x0[k] * w;
        a1 += x1[k] * w;
        a2 += x2[k] * w;
        a3 += x3[k] * w;
    }
    if (base + 0 < n) Y[(size_t)(base + 0) * 64 + lane] = a0;
    if (base + 1 < n) Y[(size_t)(base + 1) * 64 + lane] = a1;
    if (base + 2 < n) Y[(size_t)(base + 2) * 64 + lane] = a2;
    if (base + 3 < n) Y[(size_t)(base + 3) * 64 + lane] = a3;
}

// ---------------- fused aggregate: self-loop + gather + bias + relu (+ pool) ----------------
// one wave per dst node, lane = channel; unroll-4 gathers for MLP
template <int DOPOOL>
__global__ __launch_bounds__(256) void k_aggregate(const float* __restrict__ h,
                                                   const int2* __restrict__ csr,
                                                   const int* __restrict__ rowptr,
                                                   const float* __restrict__ dinv,
                                                   const float* __restrict__ b,
                                                   const int* __restrict__ batch,
                                                   float* __restrict__ hout,
                                                   float* __restrict__ pooled, int n) {
    __shared__ float red[4][64];
    __shared__ int sg[4];
    int lane = threadIdx.x & 63;
    int wave = __builtin_amdgcn_readfirstlane(threadIdx.x >> 6);
    int node = blockIdx.x * 4 + wave;
    bool active = node < n;
    float v = 0.f;
    if (active) {
        float dd = dinv[node];
        float acc = h[(size_t)node * H + lane] * dd * dd;
        int r0 = rowptr[node], r1 = rowptr[node + 1];
        int e = r0;
        for (; e + 4 <= r1; e += 4) {
            int2 p0 = csr[e + 0];
            int2 p1 = csr[e + 1];
            int2 p2 = csr[e + 2];
            int2 p3 = csr[e + 3];
            float v0 = h[(size_t)p0.x * H + lane];
            float v1 = h[(size_t)p1.x * H + lane];
            float v2 = h[(size_t)p2.x * H + lane];
            float v3 = h[(size_t)p3.x * H + lane];
            acc += v0 * __int_as_float(p0.y);
            acc += v1 * __int_as_float(p1.y);
            acc += v2 * __int_as_float(p2.y);
            acc += v3 * __int_as_float(p3.y);
        }
        for (; e < r1; ++e) {
            int2 p = csr[e];
            acc += h[(size_t)p.x * H + lane] * __int_as_float(p.y);
        }
        v = acc + b[lane];
        v = v > 0.f ? v : 0.f;
        if (!DOPOOL) hout[(size_t)node * H + lane] = v;
    }
    if (DOPOOL) {
        red[wave][lane] = active ? v : 0.f;
        if (lane == 0) sg[wave] = active ? batch[node] : -1;
        __syncthreads();
        if (wave == 0) {
            // merge runs of equal graph id (batch sorted) -> fewer atomics
            float s = red[0][lane];
            int gcur = sg[0];
            for (int w = 1; w < 4; ++w) {
                int gw = sg[w];
                if (gw < 0) break;
                if (gw == gcur) {
                    s += red[w][lane];
                } else {
                    atomicAdd(&pooled[gcur * H + lane], s);
                    s = red[w][lane];
                    gcur = gw;
                }
            }
            atomicAdd(&pooled[gcur * H + lane], s);
        }
    }
}

// ---------------- final linear ----------------
__global__ void k_final(const float* __restrict__ pooled, const float* __restrict__ gf,
                        const float* __restrict__ Wlin, const float* __restrict__ blin,
                        float* __restrict__ out) {
    int t = threadIdx.x;
    if (t >= G * OUT) return;
    int g = t >> 1, o = t & 1;
    float acc = blin[o];
#pragma unroll
    for (int j = 0; j < 64; ++j) acc += pooled[g * H + j] * Wlin[j * OUT + o];
    acc += gf[g] * Wlin[64 * OUT + o];
    out[g * OUT + o] = acc;
}

extern "C" void kernel_launch(void* const* d_in, const int* in_sizes, int n_in,
                              void* d_out, int out_size, void* d_ws, size_t ws_size,
                              hipStream_t stream) {
    const float* x          = (const float*)d_in[0];
    const int*   edge_index = (const int*)d_in[1];
    const int*   batch      = (const int*)d_in[2];
    const float* gf         = (const float*)d_in[3];
    const float* W1         = (const float*)d_in[4];
    const float* b1         = (const float*)d_in[5];
    const float* W2         = (const float*)d_in[6];
    const float* b2         = (const float*)d_in[7];
    const float* Wlin       = (const float*)d_in[8];
    const float* blin       = (const float*)d_in[9];
    float* out = (float*)d_out;

    const int N = in_sizes[0] / H;
    const int E = in_sizes[1] / 2;
    const int* src = edge_index;
    const int* dst = edge_index + E;

    // workspace layout
    float* ws = (float*)d_ws;
    float* dinv   = ws;                        // N
    float* bufA   = dinv + N;                  // N*H
    float* bufB   = bufA + (size_t)N * H;      // N*H
    float* pooled = bufB + (size_t)N * H;      // G*H
    int*   counts = (int*)(pooled + G * H);    // N
    int*   rowptr = counts + N;                // N+1
    int*   cursor = rowptr + (N + 1);          // N
    int*   blocksums = cursor + N;             // up to 256
    size_t off = (size_t)(blocksums + 256 - (int*)d_ws);
    off = (off + 1) & ~(size_t)1;
    int2*  csr    = (int2*)((int*)d_ws + off); // E int2

    const int T = 256;
    const int NB = (N + TILE - 1) / TILE;      // <=256 required

    // CSR build (also produces dinv from in-degree+1)
    k_zero_int<<<(N + T - 1) / T, T, 0, stream>>>(counts, N);
    k_hist<<<(E + T - 1) / T, T, 0, stream>>>(dst, counts, E);
    k_scan1<<<NB, TILE, 0, stream>>>(counts, rowptr, blocksums, N);
    k_scan2<<<1, 256, 0, stream>>>(blocksums, NB);
    k_scan3<<<NB, TILE, 0, stream>>>(counts, rowptr, cursor, dinv, blocksums, N, E);
    k_fill<<<(E + T - 1) / T, T, 0, stream>>>(src, dst, dinv, cursor, csr, E);

    // zero pooled (poisoned by harness)
    k_zero<<<(G * H + T - 1) / T, T, 0, stream>>>(pooled, G * H);

    // layer 1: h1 = relu(agg(x@W1) + b1)
    k_gemm64<<<(N + 15) / 16, T, 0, stream>>>(x, W1, bufA, N);
    k_aggregate<0><<<(N + 3) / 4, T, 0, stream>>>(bufA, csr, rowptr, dinv, b1, batch,
                                                  bufB, pooled, N);

    // layer 2 + fused pool
    k_gemm64<<<(N + 15) / 16, T, 0, stream>>>(bufB, W2, bufA, N);
    k_aggregate<1><<<(N + 3) / 4, T, 0, stream>>>(bufA, csr, rowptr, dinv, b2, batch,
                                                  nullptr, pooled, N);

    // head
    k_final<<<1, 128, 0, stream>>>(pooled, gf, Wlin, blin, out);
}